// Round 15
// baseline (1807.562 us; speedup 1.0000x reference)
//
#include <hip/hip_runtime.h>

#define TSTEPS 512
#define BATCH  64
#define DIN    256
#define DLAT   512

typedef _Float16 half8_t __attribute__((ext_vector_type(8)));
typedef float    f32x4  __attribute__((ext_vector_type(4)));

// d_ws layout: [0, 512K) = Wm (scan W_h frags); [512K, 768K) = Wf (W_in frags)
#define WS_WF_OFF  (512u * 1024u)
#define WS_TIER2   (512u * 1024u)
#define WS_TIER1   (768u * 1024u)

// Barrier waiting only on LDS ops (lgkmcnt), not outstanding global stores.
__device__ __forceinline__ void barrier_lds_only()
{
    __builtin_amdgcn_sched_barrier(0);
    asm volatile("s_waitcnt lgkmcnt(0)\n\ts_barrier" ::: "memory");
    __builtin_amdgcn_sched_barrier(0);
}

// ---------------- Kernel A (tier2 fallback): fp32 tiled GEMM --------------------
#define BM 64
#define BN 64
#define BK 32

__global__ __launch_bounds__(256)
void precompute_gemm(const float* __restrict__ x,
                     const float* __restrict__ Win,
                     const float* __restrict__ bh,
                     float* __restrict__ P)
{
    __shared__ float As[BM][BK + 1];
    __shared__ float Ws[BN][BK + 1];
    const int m0  = blockIdx.y * BM;
    const int n0  = blockIdx.x * BN;
    const int tid = threadIdx.x;
    const int tx  = tid & 15;
    const int ty  = tid >> 4;
    const int lr  = tid >> 2;
    const int lc  = (tid & 3) * 8;

    float acc[4][4] = {};

    for (int kk = 0; kk < DIN; kk += BK) {
        const float* ax = x   + (size_t)(m0 + lr) * DIN + kk + lc;
        const float* aw = Win + (size_t)(n0 + lr) * DIN + kk + lc;
        float4 a0 = *(const float4*)(ax);
        float4 a1 = *(const float4*)(ax + 4);
        float4 w0 = *(const float4*)(aw);
        float4 w1 = *(const float4*)(aw + 4);
        As[lr][lc+0]=a0.x; As[lr][lc+1]=a0.y; As[lr][lc+2]=a0.z; As[lr][lc+3]=a0.w;
        As[lr][lc+4]=a1.x; As[lr][lc+5]=a1.y; As[lr][lc+6]=a1.z; As[lr][lc+7]=a1.w;
        Ws[lr][lc+0]=w0.x; Ws[lr][lc+1]=w0.y; Ws[lr][lc+2]=w0.z; Ws[lr][lc+3]=w0.w;
        Ws[lr][lc+4]=w1.x; Ws[lr][lc+5]=w1.y; Ws[lr][lc+6]=w1.z; Ws[lr][lc+7]=w1.w;
        __syncthreads();
        #pragma unroll
        for (int k = 0; k < BK; ++k) {
            float a[4], w[4];
            #pragma unroll
            for (int i = 0; i < 4; ++i) a[i] = As[ty*4+i][k];
            #pragma unroll
            for (int j = 0; j < 4; ++j) w[j] = Ws[tx*4+j][k];
            #pragma unroll
            for (int i = 0; i < 4; ++i)
                #pragma unroll
                for (int j = 0; j < 4; ++j)
                    acc[i][j] += a[i] * w[j];
        }
        __syncthreads();
    }

    float4 bv = *(const float4*)(bh + n0 + tx*4);
    #pragma unroll
    for (int i = 0; i < 4; ++i) {
        float4 v;
        v.x = acc[i][0] + bv.x; v.y = acc[i][1] + bv.y;
        v.z = acc[i][2] + bv.z; v.w = acc[i][3] + bv.w;
        *(float4*)(P + (size_t)(m0 + ty*4 + i) * DLAT + n0 + tx*4) = v;
    }
}

// -------- Pack W_h into MFMA B-fragment order (fp16) ----------------------------
// Tile (kt, ntg): 32 k x 16 n; element (lane, e) = W_h[ntg*16+(lane&15)]
// [kt*32+(lane>>4)*8+e]. Flat: Wm[(tile*64+lane)*8+e], tile = kt*32+ntg.
// Verified on HW R8-R14 (absmax 0.03125).
__global__ __launch_bounds__(256)
void pack_wh_mfma(const float* __restrict__ Wh, _Float16* __restrict__ Wm)
{
    const int idx  = blockIdx.x * 256 + threadIdx.x;  // 32768 = 512 tiles x 64
    const int lane = idx & 63;
    const int tile = idx >> 6;
    const int kt   = tile >> 5;
    const int ntg  = tile & 31;
    const int n    = ntg * 16 + (lane & 15);
    const int k0   = kt * 32 + (lane >> 4) * 8;
    half8_t v;
    #pragma unroll
    for (int e = 0; e < 8; ++e)
        v[e] = (_Float16)Wh[(size_t)n * DLAT + k0 + e];
    *(half8_t*)(Wm + (size_t)idx * 8) = v;
}

// -------- Pack W_in into MFMA B-fragment order (fp16), K = DIN = 256 ------------
__global__ __launch_bounds__(256)
void pack_win_f16(const float* __restrict__ Win, _Float16* __restrict__ Wf)
{
    const int idx  = blockIdx.x * 256 + threadIdx.x;  // 16384 = 256 tiles x 64
    const int lane = idx & 63;
    const int tile = idx >> 6;
    const int kt   = tile >> 5;
    const int ntg  = tile & 31;
    const int n    = ntg * 16 + (lane & 15);
    const int k0   = kt * 32 + (lane >> 4) * 8;
    half8_t v;
    #pragma unroll
    for (int e = 0; e < 8; ++e)
        v[e] = (_Float16)Win[(size_t)n * DIN + k0 + e];
    *(half8_t*)(Wf + (size_t)idx * 8) = v;
}

// ---------------- Kernel A (tier1): f16 MFMA GEMM  P = x @ Win^T + bh -----------
__global__ __launch_bounds__(256)
void precompute_mfma(const float* __restrict__ x,
                     const half8_t* __restrict__ Wf,
                     const float* __restrict__ bh,
                     float* __restrict__ P)
{
    const int tid  = threadIdx.x;
    const int wave = tid >> 6, lane = tid & 63;
    const int wm   = wave >> 1, wn = wave & 1;
    const int m0   = (blockIdx.x >> 2) * 128 + wm * 64;
    const int n0   = (blockIdx.x & 3) * 128 + wn * 64;
    const int col  = lane & 15, rg = lane >> 4;

    float bv[4];
    #pragma unroll
    for (int nt = 0; nt < 4; ++nt) bv[nt] = bh[n0 + nt * 16 + col];

    f32x4 C[4][4] = {};

    #pragma unroll
    for (int kt = 0; kt < 8; ++kt) {
        half8_t A[4];
        #pragma unroll
        for (int mt = 0; mt < 4; ++mt) {
            const float* xp = x + (size_t)(m0 + mt * 16 + col) * DIN
                                + kt * 32 + rg * 8;
            float4 a = *(const float4*)xp;
            float4 b = *(const float4*)(xp + 4);
            half8_t v;
            v[0] = (_Float16)a.x; v[1] = (_Float16)a.y;
            v[2] = (_Float16)a.z; v[3] = (_Float16)a.w;
            v[4] = (_Float16)b.x; v[5] = (_Float16)b.y;
            v[6] = (_Float16)b.z; v[7] = (_Float16)b.w;
            A[mt] = v;
        }
        half8_t B[4];
        #pragma unroll
        for (int nt = 0; nt < 4; ++nt)
            B[nt] = Wf[(size_t)((kt * 32 + (n0 >> 4) + nt) * 64) + lane];
        #pragma unroll
        for (int mt = 0; mt < 4; ++mt)
            #pragma unroll
            for (int nt = 0; nt < 4; ++nt)
                C[mt][nt] = __builtin_amdgcn_mfma_f32_16x16x32_f16(
                                A[mt], B[nt], C[mt][nt], 0, 0, 0);
    }

    #pragma unroll
    for (int mt = 0; mt < 4; ++mt)
        #pragma unroll
        for (int nt = 0; nt < 4; ++nt) {
            #pragma unroll
            for (int r = 0; r < 4; ++r) {
                const int m = m0 + mt * 16 + rg * 4 + r;
                P[(size_t)m * DLAT + n0 + nt * 16 + col] = C[mt][nt][r] + bv[nt];
            }
        }
}

// ---------------- Kernel B: scan, B split reg / L2-global (LDS = A only) --------
// R14 structure (8 waves, stagger kt0=2w, 2-deep A prefetch, setprio, lds-only
// barrier, pre-barrier own-slice prime) with the 16 per-wave LDS B-frags moved
// to GLOBAL loads from L2-resident Wm (512 KB, step-invariant):
//  - LDS pipe (the measured wall: 256 b128/step ~ 3000 cyc) now carries only
//    A-reads: 18 instr/wave/step -> ~1200-1700 cyc.
//  - B rides the VMEM pipe; only 8 CUs/XCD active -> ample L2 BW. Bp[2][2]
//    2-deep prefetch; refills wrap cyclically (B is t-invariant, so chunk 6/7
//    refills prime next step's chunks 0/1 across the barrier for free).
// B-frags: even seg nt0-3 + odd seg nt0,1 in regs (48 = 192 regs, AGPR-
// absorbed, MFMA reads natively); odd seg nt2,3 (16) via Bp. Same summation
// order as R13/R14 -> absmax must stay exactly 0.03125.
__global__ __launch_bounds__(512, 2)
void rnn_scan_l2b(const half8_t* __restrict__ Wm,   // fragment-packed
                  const float* __restrict__ h0,
                  float* __restrict__ out)          // P in, h_seq out (in place)
{
    __shared__ _Float16 hbuf[2][DLAT];       // 2 KB, double-buffered h (only LDS)

    const int b    = blockIdx.x;
    const int tid  = threadIdx.x;
    const int w    = tid >> 6;               // wave 0..7: n-range 64w
    const int lane = tid & 63;
    const int kt0  = 2 * w;                  // stagger origin
    const int aoff = (lane >> 4) * 8;        // A-frag k sub-offset

    // ---- one-time: 48 reg B-frags (even seg all nt; odd seg nt 0,1) ----
    half8_t bfr[48];
    #pragma unroll
    for (int s = 0; s < 16; ++s) {
        const int c  = s >> 1;
        const int kt = (kt0 + s) & 15;
        #pragma unroll
        for (int nt = 0; nt < 4; ++nt) {
            if (!((s & 1) && nt >= 2))
                bfr[c * 6 + ((s & 1) ? 4 + nt : nt)] =
                    Wm[(size_t)((kt * 32 + w * 4 + nt) * 64) + lane];
        }
    }

    hbuf[0][tid] = (_Float16)h0[(size_t)b * DLAT + tid];   // pre-relu h0
    __syncthreads();

    // ---- prime: A chunks 0,1 from LDS; B (global) pairs for chunks 0,1 ----
    half8_t Ap[2][2], Bp[2][2];
    #pragma unroll
    for (int i = 0; i < 4; ++i)
        Ap[i >> 1][i & 1] =
            *(const half8_t*)&hbuf[0][((kt0 + i) & 15) * 32 + aoff];
    #pragma unroll
    for (int c0 = 0; c0 < 2; ++c0) {
        const int kt = (kt0 + 2 * c0 + 1) & 15;
        Bp[c0][0] = Wm[(size_t)((kt * 32 + w * 4 + 2) * 64) + lane];
        Bp[c0][1] = Wm[(size_t)((kt * 32 + w * 4 + 3) * 64) + lane];
    }

    for (int t = 0; t < TSTEPS; ++t) {
        const int cur = t & 1, nxt = cur ^ 1;
        float* orow = out + ((size_t)t * BATCH + b) * DLAT;
        float pv = orow[w * 64 + lane];      // prefetch P (hidden under MFMAs)

        f32x4 C[4] = {};
        __builtin_amdgcn_s_setprio(1);
        #pragma unroll
        for (int c = 0; c < 8; ++c) {        // 8 chunks x 2 segments
            const int pb = c & 1;
            // segment s = 2c (even): all 4 B from registers
            #pragma unroll
            for (int nt = 0; nt < 4; ++nt)
                C[nt] = __builtin_amdgcn_mfma_f32_16x16x32_f16(
                            Ap[pb][0], bfr[c * 6 + nt], C[nt], 0, 0, 0);
            // segment s = 2c+1 (odd): nt 0,1 reg; nt 2,3 global-prefetched
            C[0] = __builtin_amdgcn_mfma_f32_16x16x32_f16(
                        Ap[pb][1], bfr[c * 6 + 4], C[0], 0, 0, 0);
            C[1] = __builtin_amdgcn_mfma_f32_16x16x32_f16(
                        Ap[pb][1], bfr[c * 6 + 5], C[1], 0, 0, 0);
            C[2] = __builtin_amdgcn_mfma_f32_16x16x32_f16(
                        Ap[pb][1], Bp[pb][0], C[2], 0, 0, 0);
            C[3] = __builtin_amdgcn_mfma_f32_16x16x32_f16(
                        Ap[pb][1], Bp[pb][1], C[3], 0, 0, 0);
            // refill Bp[pb] with chunk (c+2)&7's pair — cyclic: chunks 6,7
            // prime next step's chunks 0,1 (B is step-invariant).
            {
                const int cc = (c + 2) & 7;
                const int kt = (kt0 + 2 * cc + 1) & 15;
                Bp[pb][0] = Wm[(size_t)((kt * 32 + w * 4 + 2) * 64) + lane];
                Bp[pb][1] = Wm[(size_t)((kt * 32 + w * 4 + 3) * 64) + lane];
            }
            if (c < 6) {                     // A-frags 2 chunks ahead (LDS)
                #pragma unroll
                for (int i = 0; i < 2; ++i) {
                    const int s = (c + 2) * 2 + i;
                    Ap[pb][i] =
                        *(const half8_t*)&hbuf[cur][((kt0 + s) & 15) * 32 + aoff];
                }
            }
        }
        __builtin_amdgcn_s_setprio(0);

        // epilogue: lane L owns n = 64w + L; all C rows equal (broadcast A)
        const int g4 = lane >> 4;
        float m = (g4 == 0) ? C[0][0]
                : (g4 == 1) ? C[1][0]
                : (g4 == 2) ? C[2][0]
                :             C[3][0];
        float v = fmaxf(m + pv, 0.f);
        orow[w * 64 + lane] = v;             // HBM store: drains lazily
        hbuf[nxt][w * 64 + lane] = (_Float16)v;

        // pre-barrier prime: next step's chunk 0 A = OWN slice (just written;
        // same-wave DS ordering makes the read-back legal before the barrier).
        Ap[0][0] = *(const half8_t*)&hbuf[nxt][((kt0 + 0) & 15) * 32 + aoff];
        Ap[0][1] = *(const half8_t*)&hbuf[nxt][((kt0 + 1) & 15) * 32 + aoff];

        barrier_lds_only();                  // wait LDS only; not the HBM store

        // post-barrier: chunk 1 A-frags (other waves' h, now published)
        Ap[1][0] = *(const half8_t*)&hbuf[nxt][((kt0 + 2) & 15) * 32 + aoff];
        Ap[1][1] = *(const half8_t*)&hbuf[nxt][((kt0 + 3) & 15) * 32 + aoff];
    }
}

// ---------------- Fallback (no workspace): row-major W_h, one row per thread ----
__global__ __launch_bounds__(512)
void rnn_scan_row(const float* __restrict__ Wh,
                  const float* __restrict__ h0,
                  float* __restrict__ out)
{
    __shared__ float h[DLAT];
    const int b = blockIdx.x;
    const int r = threadIdx.x;
    h[r] = h0[(size_t)b * DLAT + r];
    __syncthreads();
    const float* wrow = Wh + (size_t)r * DLAT;
    for (int t = 0; t < TSTEPS; ++t) {
        float* orow = out + ((size_t)t * BATCH + b) * DLAT;
        float acc = orow[r];
        #pragma unroll 8
        for (int k = 0; k < DLAT; k += 4) {
            float4 w  = *(const float4*)(wrow + k);
            float4 hv = *(const float4*)&h[k];
            acc += w.x*hv.x + w.y*hv.y + w.z*hv.z + w.w*hv.w;
        }
        float v = fmaxf(acc, 0.f);
        __syncthreads();
        h[r] = v;
        orow[r] = v;
        __syncthreads();
    }
}

extern "C" void kernel_launch(void* const* d_in, const int* in_sizes, int n_in,
                              void* d_out, int out_size, void* d_ws, size_t ws_size,
                              hipStream_t stream)
{
    const float* x    = (const float*)d_in[0];
    const float* h0   = (const float*)d_in[1];
    const float* Win  = (const float*)d_in[2];
    const float* Wh   = (const float*)d_in[3];
    const float* bh   = (const float*)d_in[4];
    float* out = (float*)d_out;

    if (ws_size >= WS_TIER1) {
        _Float16* Wm = (_Float16*)d_ws;
        _Float16* Wf = (_Float16*)((char*)d_ws + WS_WF_OFF);
        pack_wh_mfma<<<128, 256, 0, stream>>>(Wh, Wm);
        pack_win_f16<<<64, 256, 0, stream>>>(Win, Wf);
        precompute_mfma<<<1024, 256, 0, stream>>>(x, (const half8_t*)Wf, bh, out);
        rnn_scan_l2b<<<BATCH, 512, 0, stream>>>((const half8_t*)Wm, h0, out);
    } else if (ws_size >= WS_TIER2) {
        _Float16* Wm = (_Float16*)d_ws;
        dim3 gA(DLAT / BN, (TSTEPS * BATCH) / BM);   // (8, 512)
        pack_wh_mfma<<<128, 256, 0, stream>>>(Wh, Wm);
        precompute_gemm<<<gA, 256, 0, stream>>>(x, Win, bh, out);
        rnn_scan_l2b<<<BATCH, 512, 0, stream>>>((const half8_t*)Wm, h0, out);
    } else {
        dim3 gA(DLAT / BN, (TSTEPS * BATCH) / BM);
        precompute_gemm<<<gA, 256, 0, stream>>>(x, Win, bh, out);
        rnn_scan_row<<<BATCH, 512, 0, stream>>>(Wh, h0, out);
    }
}

// Round 16
// 637.618 us; speedup vs baseline: 2.8349x; 2.8349x over previous
//
#include <hip/hip_runtime.h>

#define TSTEPS 512
#define BATCH  64
#define DIN    256
#define DLAT   512

typedef _Float16 half8_t __attribute__((ext_vector_type(8)));
typedef float    f32x4  __attribute__((ext_vector_type(4)));

// d_ws layout: [0, 512K) = Wm (scan W_h frags); [512K, 768K) = Wf (W_in frags)
#define WS_WF_OFF  (512u * 1024u)
#define WS_TIER2   (512u * 1024u)
#define WS_TIER1   (768u * 1024u)

// Barrier waiting only on LDS ops (lgkmcnt), not outstanding global stores.
__device__ __forceinline__ void barrier_lds_only()
{
    __builtin_amdgcn_sched_barrier(0);
    asm volatile("s_waitcnt lgkmcnt(0)\n\ts_barrier" ::: "memory");
    __builtin_amdgcn_sched_barrier(0);
}

// ---------------- Kernel A (tier2 fallback): fp32 tiled GEMM --------------------
#define BM 64
#define BN 64
#define BK 32

__global__ __launch_bounds__(256)
void precompute_gemm(const float* __restrict__ x,
                     const float* __restrict__ Win,
                     const float* __restrict__ bh,
                     float* __restrict__ P)
{
    __shared__ float As[BM][BK + 1];
    __shared__ float Ws[BN][BK + 1];
    const int m0  = blockIdx.y * BM;
    const int n0  = blockIdx.x * BN;
    const int tid = threadIdx.x;
    const int tx  = tid & 15;
    const int ty  = tid >> 4;
    const int lr  = tid >> 2;
    const int lc  = (tid & 3) * 8;

    float acc[4][4] = {};

    for (int kk = 0; kk < DIN; kk += BK) {
        const float* ax = x   + (size_t)(m0 + lr) * DIN + kk + lc;
        const float* aw = Win + (size_t)(n0 + lr) * DIN + kk + lc;
        float4 a0 = *(const float4*)(ax);
        float4 a1 = *(const float4*)(ax + 4);
        float4 w0 = *(const float4*)(aw);
        float4 w1 = *(const float4*)(aw + 4);
        As[lr][lc+0]=a0.x; As[lr][lc+1]=a0.y; As[lr][lc+2]=a0.z; As[lr][lc+3]=a0.w;
        As[lr][lc+4]=a1.x; As[lr][lc+5]=a1.y; As[lr][lc+6]=a1.z; As[lr][lc+7]=a1.w;
        Ws[lr][lc+0]=w0.x; Ws[lr][lc+1]=w0.y; Ws[lr][lc+2]=w0.z; Ws[lr][lc+3]=w0.w;
        Ws[lr][lc+4]=w1.x; Ws[lr][lc+5]=w1.y; Ws[lr][lc+6]=w1.z; Ws[lr][lc+7]=w1.w;
        __syncthreads();
        #pragma unroll
        for (int k = 0; k < BK; ++k) {
            float a[4], w[4];
            #pragma unroll
            for (int i = 0; i < 4; ++i) a[i] = As[ty*4+i][k];
            #pragma unroll
            for (int j = 0; j < 4; ++j) w[j] = Ws[tx*4+j][k];
            #pragma unroll
            for (int i = 0; i < 4; ++i)
                #pragma unroll
                for (int j = 0; j < 4; ++j)
                    acc[i][j] += a[i] * w[j];
        }
        __syncthreads();
    }

    float4 bv = *(const float4*)(bh + n0 + tx*4);
    #pragma unroll
    for (int i = 0; i < 4; ++i) {
        float4 v;
        v.x = acc[i][0] + bv.x; v.y = acc[i][1] + bv.y;
        v.z = acc[i][2] + bv.z; v.w = acc[i][3] + bv.w;
        *(float4*)(P + (size_t)(m0 + ty*4 + i) * DLAT + n0 + tx*4) = v;
    }
}

// -------- Pack W_h into MFMA B-fragment order (fp16) ----------------------------
// Tile (kt, ntg): 32 k x 16 n; element (lane, e) = W_h[ntg*16+(lane&15)]
// [kt*32+(lane>>4)*8+e]. Flat: Wm[(tile*64+lane)*8+e], tile = kt*32+ntg.
// Verified on HW R8-R15 (absmax 0.03125).
__global__ __launch_bounds__(256)
void pack_wh_mfma(const float* __restrict__ Wh, _Float16* __restrict__ Wm)
{
    const int idx  = blockIdx.x * 256 + threadIdx.x;  // 32768 = 512 tiles x 64
    const int lane = idx & 63;
    const int tile = idx >> 6;
    const int kt   = tile >> 5;
    const int ntg  = tile & 31;
    const int n    = ntg * 16 + (lane & 15);
    const int k0   = kt * 32 + (lane >> 4) * 8;
    half8_t v;
    #pragma unroll
    for (int e = 0; e < 8; ++e)
        v[e] = (_Float16)Wh[(size_t)n * DLAT + k0 + e];
    *(half8_t*)(Wm + (size_t)idx * 8) = v;
}

// -------- Pack W_in into MFMA B-fragment order (fp16), K = DIN = 256 ------------
__global__ __launch_bounds__(256)
void pack_win_f16(const float* __restrict__ Win, _Float16* __restrict__ Wf)
{
    const int idx  = blockIdx.x * 256 + threadIdx.x;  // 16384 = 256 tiles x 64
    const int lane = idx & 63;
    const int tile = idx >> 6;
    const int kt   = tile >> 5;
    const int ntg  = tile & 31;
    const int n    = ntg * 16 + (lane & 15);
    const int k0   = kt * 32 + (lane >> 4) * 8;
    half8_t v;
    #pragma unroll
    for (int e = 0; e < 8; ++e)
        v[e] = (_Float16)Win[(size_t)n * DIN + k0 + e];
    *(half8_t*)(Wf + (size_t)idx * 8) = v;
}

// ---------------- Kernel A (tier1): f16 MFMA GEMM  P = x @ Win^T + bh -----------
__global__ __launch_bounds__(256)
void precompute_mfma(const float* __restrict__ x,
                     const half8_t* __restrict__ Wf,
                     const float* __restrict__ bh,
                     float* __restrict__ P)
{
    const int tid  = threadIdx.x;
    const int wave = tid >> 6, lane = tid & 63;
    const int wm   = wave >> 1, wn = wave & 1;
    const int m0   = (blockIdx.x >> 2) * 128 + wm * 64;
    const int n0   = (blockIdx.x & 3) * 128 + wn * 64;
    const int col  = lane & 15, rg = lane >> 4;

    float bv[4];
    #pragma unroll
    for (int nt = 0; nt < 4; ++nt) bv[nt] = bh[n0 + nt * 16 + col];

    f32x4 C[4][4] = {};

    #pragma unroll
    for (int kt = 0; kt < 8; ++kt) {
        half8_t A[4];
        #pragma unroll
        for (int mt = 0; mt < 4; ++mt) {
            const float* xp = x + (size_t)(m0 + mt * 16 + col) * DIN
                                + kt * 32 + rg * 8;
            float4 a = *(const float4*)xp;
            float4 b = *(const float4*)(xp + 4);
            half8_t v;
            v[0] = (_Float16)a.x; v[1] = (_Float16)a.y;
            v[2] = (_Float16)a.z; v[3] = (_Float16)a.w;
            v[4] = (_Float16)b.x; v[5] = (_Float16)b.y;
            v[6] = (_Float16)b.z; v[7] = (_Float16)b.w;
            A[mt] = v;
        }
        half8_t B[4];
        #pragma unroll
        for (int nt = 0; nt < 4; ++nt)
            B[nt] = Wf[(size_t)((kt * 32 + (n0 >> 4) + nt) * 64) + lane];
        #pragma unroll
        for (int mt = 0; mt < 4; ++mt)
            #pragma unroll
            for (int nt = 0; nt < 4; ++nt)
                C[mt][nt] = __builtin_amdgcn_mfma_f32_16x16x32_f16(
                                A[mt], B[nt], C[mt][nt], 0, 0, 0);
    }

    #pragma unroll
    for (int mt = 0; mt < 4; ++mt)
        #pragma unroll
        for (int nt = 0; nt < 4; ++nt) {
            #pragma unroll
            for (int r = 0; r < 4; ++r) {
                const int m = m0 + mt * 16 + rg * 4 + r;
                P[(size_t)m * DLAT + n0 + nt * 16 + col] = C[mt][nt][r] + bv[nt];
            }
        }
}

// ---------------- Kernel B: R14 scan + barrier-shadow chunk-0 execution ---------
// R14 structure (8 waves, stagger kt0=2w, 2-deep A prefetch, B spread 2/chunk in
// LDS + 1-ahead Bp prefetch, setprio, lds-only barrier). NEW: step t+1's
// chunk 0 (kt0,kt0+1) depends only on the wave's OWN h-slice + reg/LDS B, so
// its C-init + 8 MFMAs execute BEFORE the barrier (s_barrier doesn't wait on
// the MFMA pipe -> the MFMAs and their operand latency hide in the barrier
// shadow). pvt (P row for t+1) also prefetched pre-barrier. Post-barrier loads
// chunk 1+2 A-frags (chunk 1 first; fine-grained lgkmcnt starts MFMAs after 2
// reads). Summation order identical to R13/R14 -> absmax exactly 0.03125.
__global__ __launch_bounds__(512, 2)
void rnn_scan_pb(const half8_t* __restrict__ Wm,   // fragment-packed
                 const float* __restrict__ h0,
                 float* __restrict__ out)          // P in, h_seq out (in place)
{
    __shared__ half8_t  ldsB[8 * 16 * 64];   // 128 KB: [(w*16 + slot)*64 + lane]
    __shared__ _Float16 hbuf[2][DLAT];       // 2 KB, double-buffered h

    const int b    = blockIdx.x;
    const int tid  = threadIdx.x;
    const int w    = tid >> 6;               // wave 0..7: n-range 64w
    const int lane = tid & 63;
    const int kt0  = 2 * w;                  // stagger origin
    const int aoff = (lane >> 4) * 8;        // A-frag k sub-offset

    // ---- one-time: B frags; LDS frags = odd s, nt>=2 (2 per chunk) ----
    half8_t bfr[48];
    #pragma unroll
    for (int s = 0; s < 16; ++s) {
        const int c  = s >> 1;
        const int kt = (kt0 + s) & 15;
        #pragma unroll
        for (int nt = 0; nt < 4; ++nt) {
            half8_t v = Wm[(size_t)((kt * 32 + w * 4 + nt) * 64) + lane];
            if ((s & 1) && nt >= 2) ldsB[(w * 16 + c * 2 + (nt - 2)) * 64 + lane] = v;
            else                    bfr[c * 6 + ((s & 1) ? 4 + nt : nt)] = v;
        }
    }

    hbuf[0][tid] = (_Float16)h0[(size_t)b * DLAT + tid];   // pre-relu h0
    __syncthreads();

    // 8 MFMAs of chunk 0 (segments 0,1) from Ap[0], bfr[0..5], Bp[0..1]
#define CHUNK0_EXEC()                                                          \
    do {                                                                       \
        C[0] = __builtin_amdgcn_mfma_f32_16x16x32_f16(Ap[0][0], bfr[0], C[0], 0, 0, 0); \
        C[1] = __builtin_amdgcn_mfma_f32_16x16x32_f16(Ap[0][0], bfr[1], C[1], 0, 0, 0); \
        C[2] = __builtin_amdgcn_mfma_f32_16x16x32_f16(Ap[0][0], bfr[2], C[2], 0, 0, 0); \
        C[3] = __builtin_amdgcn_mfma_f32_16x16x32_f16(Ap[0][0], bfr[3], C[3], 0, 0, 0); \
        C[0] = __builtin_amdgcn_mfma_f32_16x16x32_f16(Ap[0][1], bfr[4], C[0], 0, 0, 0); \
        C[1] = __builtin_amdgcn_mfma_f32_16x16x32_f16(Ap[0][1], bfr[5], C[1], 0, 0, 0); \
        C[2] = __builtin_amdgcn_mfma_f32_16x16x32_f16(Ap[0][1], Bp[0],  C[2], 0, 0, 0); \
        C[3] = __builtin_amdgcn_mfma_f32_16x16x32_f16(Ap[0][1], Bp[1],  C[3], 0, 0, 0); \
    } while (0)

    // ---- prologue (step 0): prime + chunk-0 exec + chunk-1 primes ----
    half8_t Ap[2][2], Bp[2];
    f32x4 C[4] = {};
    Ap[0][0] = *(const half8_t*)&hbuf[0][((kt0 + 0) & 15) * 32 + aoff];
    Ap[0][1] = *(const half8_t*)&hbuf[0][((kt0 + 1) & 15) * 32 + aoff];
    Bp[0] = ldsB[(w * 16 + 0) * 64 + lane];
    Bp[1] = ldsB[(w * 16 + 1) * 64 + lane];
    CHUNK0_EXEC();
    Bp[0] = ldsB[(w * 16 + 2) * 64 + lane];   // chunk 1 pair
    Bp[1] = ldsB[(w * 16 + 3) * 64 + lane];
    Ap[1][0] = *(const half8_t*)&hbuf[0][((kt0 + 2) & 15) * 32 + aoff];
    Ap[1][1] = *(const half8_t*)&hbuf[0][((kt0 + 3) & 15) * 32 + aoff];
    Ap[0][0] = *(const half8_t*)&hbuf[0][((kt0 + 4) & 15) * 32 + aoff];
    Ap[0][1] = *(const half8_t*)&hbuf[0][((kt0 + 5) & 15) * 32 + aoff];
    float pvt = out[(size_t)0 * BATCH * DLAT + (size_t)b * DLAT + w * 64 + lane];

    for (int t = 0; t < TSTEPS; ++t) {
        const int cur = t & 1, nxt = cur ^ 1;

        __builtin_amdgcn_s_setprio(1);
        #pragma unroll
        for (int c = 1; c < 8; ++c) {        // chunks 1..7 (chunk 0 pre-done)
            const int pb = c & 1;
            // segment s = 2c (even): all 4 B from registers
            #pragma unroll
            for (int nt = 0; nt < 4; ++nt)
                C[nt] = __builtin_amdgcn_mfma_f32_16x16x32_f16(
                            Ap[pb][0], bfr[c * 6 + nt], C[nt], 0, 0, 0);
            // segment s = 2c+1 (odd): nt 0,1 reg; nt 2,3 prefetched LDS
            C[0] = __builtin_amdgcn_mfma_f32_16x16x32_f16(
                        Ap[pb][1], bfr[c * 6 + 4], C[0], 0, 0, 0);
            C[1] = __builtin_amdgcn_mfma_f32_16x16x32_f16(
                        Ap[pb][1], bfr[c * 6 + 5], C[1], 0, 0, 0);
            C[2] = __builtin_amdgcn_mfma_f32_16x16x32_f16(
                        Ap[pb][1], Bp[0], C[2], 0, 0, 0);
            C[3] = __builtin_amdgcn_mfma_f32_16x16x32_f16(
                        Ap[pb][1], Bp[1], C[3], 0, 0, 0);
            if (c < 7) {                     // next chunk's 2 LDS B-frags
                Bp[0] = ldsB[(w * 16 + (c + 1) * 2 + 0) * 64 + lane];
                Bp[1] = ldsB[(w * 16 + (c + 1) * 2 + 1) * 64 + lane];
            }
            if (c >= 1 && c < 6) {           // A-frags 2 chunks ahead (3..7)
                #pragma unroll
                for (int i = 0; i < 2; ++i) {
                    const int s = (c + 2) * 2 + i;
                    Ap[pb][i] =
                        *(const half8_t*)&hbuf[cur][((kt0 + s) & 15) * 32 + aoff];
                }
            }
        }
        __builtin_amdgcn_s_setprio(0);

        // epilogue: lane L owns n = 64w + L; all C rows equal (broadcast A)
        const int g4 = lane >> 4;
        float m = (g4 == 0) ? C[0][0]
                : (g4 == 1) ? C[1][0]
                : (g4 == 2) ? C[2][0]
                :             C[3][0];
        float v = fmaxf(m + pvt, 0.f);
        float* orow = out + ((size_t)t * BATCH + b) * DLAT;
        orow[w * 64 + lane] = v;             // HBM store: drains lazily
        hbuf[nxt][w * 64 + lane] = (_Float16)v;

        // ---- barrier-shadow tail: step t+1 chunk 0 (own slice) ----
        const int t2 = (t + 1 < TSTEPS) ? t + 1 : t;      // safe P prefetch
        pvt = out[((size_t)t2 * BATCH + b) * DLAT + w * 64 + lane];
        Ap[0][0] = *(const half8_t*)&hbuf[nxt][((kt0 + 0) & 15) * 32 + aoff];
        Ap[0][1] = *(const half8_t*)&hbuf[nxt][((kt0 + 1) & 15) * 32 + aoff];
        Bp[0] = ldsB[(w * 16 + 0) * 64 + lane];           // chunk 0 pair
        Bp[1] = ldsB[(w * 16 + 1) * 64 + lane];
        #pragma unroll
        for (int nt = 0; nt < 4; ++nt) C[nt] = (f32x4){0.f, 0.f, 0.f, 0.f};
        CHUNK0_EXEC();                       // latency hides under the barrier
        Bp[0] = ldsB[(w * 16 + 2) * 64 + lane];           // chunk 1 pair
        Bp[1] = ldsB[(w * 16 + 3) * 64 + lane];

        barrier_lds_only();                  // wait LDS only; not the HBM store

        // post-barrier: chunk 1 + 2 A-frags (other waves' h, now published)
        Ap[1][0] = *(const half8_t*)&hbuf[nxt][((kt0 + 2) & 15) * 32 + aoff];
        Ap[1][1] = *(const half8_t*)&hbuf[nxt][((kt0 + 3) & 15) * 32 + aoff];
        Ap[0][0] = *(const half8_t*)&hbuf[nxt][((kt0 + 4) & 15) * 32 + aoff];
        Ap[0][1] = *(const half8_t*)&hbuf[nxt][((kt0 + 5) & 15) * 32 + aoff];
    }
#undef CHUNK0_EXEC
}

// ---------------- Fallback (no workspace): row-major W_h, one row per thread ----
__global__ __launch_bounds__(512)
void rnn_scan_row(const float* __restrict__ Wh,
                  const float* __restrict__ h0,
                  float* __restrict__ out)
{
    __shared__ float h[DLAT];
    const int b = blockIdx.x;
    const int r = threadIdx.x;
    h[r] = h0[(size_t)b * DLAT + r];
    __syncthreads();
    const float* wrow = Wh + (size_t)r * DLAT;
    for (int t = 0; t < TSTEPS; ++t) {
        float* orow = out + ((size_t)t * BATCH + b) * DLAT;
        float acc = orow[r];
        #pragma unroll 8
        for (int k = 0; k < DLAT; k += 4) {
            float4 w  = *(const float4*)(wrow + k);
            float4 hv = *(const float4*)&h[k];
            acc += w.x*hv.x + w.y*hv.y + w.z*hv.z + w.w*hv.w;
        }
        float v = fmaxf(acc, 0.f);
        __syncthreads();
        h[r] = v;
        orow[r] = v;
        __syncthreads();
    }
}

extern "C" void kernel_launch(void* const* d_in, const int* in_sizes, int n_in,
                              void* d_out, int out_size, void* d_ws, size_t ws_size,
                              hipStream_t stream)
{
    const float* x    = (const float*)d_in[0];
    const float* h0   = (const float*)d_in[1];
    const float* Win  = (const float*)d_in[2];
    const float* Wh   = (const float*)d_in[3];
    const float* bh   = (const float*)d_in[4];
    float* out = (float*)d_out;

    if (ws_size >= WS_TIER1) {
        _Float16* Wm = (_Float16*)d_ws;
        _Float16* Wf = (_Float16*)((char*)d_ws + WS_WF_OFF);
        pack_wh_mfma<<<128, 256, 0, stream>>>(Wh, Wm);
        pack_win_f16<<<64, 256, 0, stream>>>(Win, Wf);
        precompute_mfma<<<1024, 256, 0, stream>>>(x, (const half8_t*)Wf, bh, out);
        rnn_scan_pb<<<BATCH, 512, 0, stream>>>((const half8_t*)Wm, h0, out);
    } else if (ws_size >= WS_TIER2) {
        _Float16* Wm = (_Float16*)d_ws;
        dim3 gA(DLAT / BN, (TSTEPS * BATCH) / BM);   // (8, 512)
        pack_wh_mfma<<<128, 256, 0, stream>>>(Wh, Wm);
        precompute_gemm<<<gA, 256, 0, stream>>>(x, Win, bh, out);
        rnn_scan_pb<<<BATCH, 512, 0, stream>>>((const half8_t*)Wm, h0, out);
    } else {
        dim3 gA(DLAT / BN, (TSTEPS * BATCH) / BM);
        precompute_gemm<<<gA, 256, 0, stream>>>(x, Win, bh, out);
        rnn_scan_row<<<BATCH, 512, 0, stream>>>(Wh, h0, out);
    }
}

// Round 17
// 630.662 us; speedup vs baseline: 2.8661x; 1.0110x over previous
//
#include <hip/hip_runtime.h>

#define TSTEPS 512
#define BATCH  64
#define DIN    256
#define DLAT   512

typedef _Float16 half8_t __attribute__((ext_vector_type(8)));
typedef float    f32x4  __attribute__((ext_vector_type(4)));

// d_ws layout: [0, 512K) = Wm (scan W_h frags); [512K, 768K) = Wf (W_in frags)
#define WS_WF_OFF  (512u * 1024u)
#define WS_TIER2   (512u * 1024u)
#define WS_TIER1   (768u * 1024u)

// Barrier waiting only on LDS ops (lgkmcnt), not outstanding global stores.
__device__ __forceinline__ void barrier_lds_only()
{
    __builtin_amdgcn_sched_barrier(0);
    asm volatile("s_waitcnt lgkmcnt(0)\n\ts_barrier" ::: "memory");
    __builtin_amdgcn_sched_barrier(0);
}

// ---------------- Kernel A (tier2 fallback): fp32 tiled GEMM --------------------
#define BM 64
#define BN 64
#define BK 32

__global__ __launch_bounds__(256)
void precompute_gemm(const float* __restrict__ x,
                     const float* __restrict__ Win,
                     const float* __restrict__ bh,
                     float* __restrict__ P)
{
    __shared__ float As[BM][BK + 1];
    __shared__ float Ws[BN][BK + 1];
    const int m0  = blockIdx.y * BM;
    const int n0  = blockIdx.x * BN;
    const int tid = threadIdx.x;
    const int tx  = tid & 15;
    const int ty  = tid >> 4;
    const int lr  = tid >> 2;
    const int lc  = (tid & 3) * 8;

    float acc[4][4] = {};

    for (int kk = 0; kk < DIN; kk += BK) {
        const float* ax = x   + (size_t)(m0 + lr) * DIN + kk + lc;
        const float* aw = Win + (size_t)(n0 + lr) * DIN + kk + lc;
        float4 a0 = *(const float4*)(ax);
        float4 a1 = *(const float4*)(ax + 4);
        float4 w0 = *(const float4*)(aw);
        float4 w1 = *(const float4*)(aw + 4);
        As[lr][lc+0]=a0.x; As[lr][lc+1]=a0.y; As[lr][lc+2]=a0.z; As[lr][lc+3]=a0.w;
        As[lr][lc+4]=a1.x; As[lr][lc+5]=a1.y; As[lr][lc+6]=a1.z; As[lr][lc+7]=a1.w;
        Ws[lr][lc+0]=w0.x; Ws[lr][lc+1]=w0.y; Ws[lr][lc+2]=w0.z; Ws[lr][lc+3]=w0.w;
        Ws[lr][lc+4]=w1.x; Ws[lr][lc+5]=w1.y; Ws[lr][lc+6]=w1.z; Ws[lr][lc+7]=w1.w;
        __syncthreads();
        #pragma unroll
        for (int k = 0; k < BK; ++k) {
            float a[4], w[4];
            #pragma unroll
            for (int i = 0; i < 4; ++i) a[i] = As[ty*4+i][k];
            #pragma unroll
            for (int j = 0; j < 4; ++j) w[j] = Ws[tx*4+j][k];
            #pragma unroll
            for (int i = 0; i < 4; ++i)
                #pragma unroll
                for (int j = 0; j < 4; ++j)
                    acc[i][j] += a[i] * w[j];
        }
        __syncthreads();
    }

    float4 bv = *(const float4*)(bh + n0 + tx*4);
    #pragma unroll
    for (int i = 0; i < 4; ++i) {
        float4 v;
        v.x = acc[i][0] + bv.x; v.y = acc[i][1] + bv.y;
        v.z = acc[i][2] + bv.z; v.w = acc[i][3] + bv.w;
        *(float4*)(P + (size_t)(m0 + ty*4 + i) * DLAT + n0 + tx*4) = v;
    }
}

// -------- Fused pack: W_h and W_in into MFMA B-fragment order (fp16) ------------
// Blocks 0..127: Wm tiles (kt in [0,16), ntg in [0,32), K=DLAT).
// Blocks 128..191: Wf tiles (kt in [0,8), ntg in [0,32), K=DIN).
// Fragment (lane, e) = W[n = ntg*16 + (lane&15)][k = kt*32 + (lane>>4)*8 + e].
// Layout verified on HW R8-R16 (absmax 0.03125).
__global__ __launch_bounds__(256)
void pack_both(const float* __restrict__ Wh, _Float16* __restrict__ Wm,
               const float* __restrict__ Win, _Float16* __restrict__ Wf)
{
    if (blockIdx.x < 128) {
        const int idx  = blockIdx.x * 256 + threadIdx.x;  // 32768 = 512 tiles x 64
        const int lane = idx & 63;
        const int tile = idx >> 6;
        const int kt   = tile >> 5;
        const int ntg  = tile & 31;
        const int n    = ntg * 16 + (lane & 15);
        const int k0   = kt * 32 + (lane >> 4) * 8;
        half8_t v;
        #pragma unroll
        for (int e = 0; e < 8; ++e)
            v[e] = (_Float16)Wh[(size_t)n * DLAT + k0 + e];
        *(half8_t*)(Wm + (size_t)idx * 8) = v;
    } else {
        const int idx  = (blockIdx.x - 128) * 256 + threadIdx.x;  // 16384
        const int lane = idx & 63;
        const int tile = idx >> 6;
        const int kt   = tile >> 5;
        const int ntg  = tile & 31;
        const int n    = ntg * 16 + (lane & 15);
        const int k0   = kt * 32 + (lane >> 4) * 8;
        half8_t v;
        #pragma unroll
        for (int e = 0; e < 8; ++e)
            v[e] = (_Float16)Win[(size_t)n * DIN + k0 + e];
        *(half8_t*)(Wf + (size_t)idx * 8) = v;
    }
}

// ---------------- Kernel A (tier1): f16 MFMA GEMM  P = x @ Win^T + bh -----------
__global__ __launch_bounds__(256)
void precompute_mfma(const float* __restrict__ x,
                     const half8_t* __restrict__ Wf,
                     const float* __restrict__ bh,
                     float* __restrict__ P)
{
    const int tid  = threadIdx.x;
    const int wave = tid >> 6, lane = tid & 63;
    const int wm   = wave >> 1, wn = wave & 1;
    const int m0   = (blockIdx.x >> 2) * 128 + wm * 64;
    const int n0   = (blockIdx.x & 3) * 128 + wn * 64;
    const int col  = lane & 15, rg = lane >> 4;

    float bv[4];
    #pragma unroll
    for (int nt = 0; nt < 4; ++nt) bv[nt] = bh[n0 + nt * 16 + col];

    f32x4 C[4][4] = {};

    #pragma unroll
    for (int kt = 0; kt < 8; ++kt) {
        half8_t A[4];
        #pragma unroll
        for (int mt = 0; mt < 4; ++mt) {
            const float* xp = x + (size_t)(m0 + mt * 16 + col) * DIN
                                + kt * 32 + rg * 8;
            float4 a = *(const float4*)xp;
            float4 b = *(const float4*)(xp + 4);
            half8_t v;
            v[0] = (_Float16)a.x; v[1] = (_Float16)a.y;
            v[2] = (_Float16)a.z; v[3] = (_Float16)a.w;
            v[4] = (_Float16)b.x; v[5] = (_Float16)b.y;
            v[6] = (_Float16)b.z; v[7] = (_Float16)b.w;
            A[mt] = v;
        }
        half8_t B[4];
        #pragma unroll
        for (int nt = 0; nt < 4; ++nt)
            B[nt] = Wf[(size_t)((kt * 32 + (n0 >> 4) + nt) * 64) + lane];
        #pragma unroll
        for (int mt = 0; mt < 4; ++mt)
            #pragma unroll
            for (int nt = 0; nt < 4; ++nt)
                C[mt][nt] = __builtin_amdgcn_mfma_f32_16x16x32_f16(
                                A[mt], B[nt], C[mt][nt], 0, 0, 0);
    }

    #pragma unroll
    for (int mt = 0; mt < 4; ++mt)
        #pragma unroll
        for (int nt = 0; nt < 4; ++nt) {
            #pragma unroll
            for (int r = 0; r < 4; ++r) {
                const int m = m0 + mt * 16 + rg * 4 + r;
                P[(size_t)m * DLAT + n0 + nt * 16 + col] = C[mt][nt][r] + bv[nt];
            }
        }
}

// ---------------- Kernel B: R16 scan + all-register chunk 0 ---------------------
// R16 structure (8 waves, stagger kt0=2w, 2-deep A prefetch, B prefetch, setprio,
// lds-only barrier, barrier-shadow chunk-0 exec). NEW: chunk 0 is ALL-REGISTER
// (8 bfr frags) so the barrier-shadow tail has ZERO B LDS reads on its critical
// path; chunk 7 donates 2 frags to LDS (even nt2,3 -> slots 14,15) prefetched
// into Bq at c=4 (~2-chunk lookahead). Frag->storage remap only; compute order
// identical to R13-R16 -> absmax must stay exactly 0.03125.
// bfr[48]: c0: 0-7 (even nt0-3, odd nt0-3); c1-6: 8+(c-1)*6+j (j0-3 even,
// j4-5 odd nt0,1); c7: 44,45 even nt0,1; 46,47 odd nt0,1.
// ldsB 16 slots: c1-7 odd nt2,3 -> (c-1)*2,+1 (0-13); c7 even nt2,3 -> 14,15.
__global__ __launch_bounds__(512, 2)
void rnn_scan_c0(const half8_t* __restrict__ Wm,   // fragment-packed
                 const float* __restrict__ h0,
                 float* __restrict__ out)          // P in, h_seq out (in place)
{
    __shared__ half8_t  ldsB[8 * 16 * 64];   // 128 KB: [(w*16 + slot)*64 + lane]
    __shared__ _Float16 hbuf[2][DLAT];       // 2 KB, double-buffered h

    const int b    = blockIdx.x;
    const int tid  = threadIdx.x;
    const int w    = tid >> 6;               // wave 0..7: n-range 64w
    const int lane = tid & 63;
    const int kt0  = 2 * w;                  // stagger origin
    const int aoff = (lane >> 4) * 8;        // A-frag k sub-offset

    // ---- one-time: B frags into bfr / ldsB per the remap above ----
    half8_t bfr[48];
    #pragma unroll
    for (int s = 0; s < 16; ++s) {
        const int c  = s >> 1;
        const int kt = (kt0 + s) & 15;
        #pragma unroll
        for (int nt = 0; nt < 4; ++nt) {
            half8_t v = Wm[(size_t)((kt * 32 + w * 4 + nt) * 64) + lane];
            if (c == 0) {
                bfr[(s & 1) * 4 + nt] = v;                     // 0-7
            } else if (c < 7) {
                if ((s & 1) && nt >= 2)
                    ldsB[(w * 16 + (c - 1) * 2 + (nt - 2)) * 64 + lane] = v;
                else
                    bfr[8 + (c - 1) * 6 + ((s & 1) ? 4 + nt : nt)] = v;
            } else {                                           // c == 7
                if (!(s & 1)) {                                // even seg
                    if (nt < 2) bfr[44 + nt] = v;
                    else        ldsB[(w * 16 + 14 + (nt - 2)) * 64 + lane] = v;
                } else {                                       // odd seg
                    if (nt < 2) bfr[46 + nt] = v;
                    else        ldsB[(w * 16 + 12 + (nt - 2)) * 64 + lane] = v;
                }
            }
        }
    }

    hbuf[0][tid] = (_Float16)h0[(size_t)b * DLAT + tid];   // pre-relu h0
    __syncthreads();

    // 8 MFMAs of chunk 0 — ALL register operands (bfr[0..7])
#define CHUNK0_EXEC()                                                          \
    do {                                                                       \
        C[0] = __builtin_amdgcn_mfma_f32_16x16x32_f16(Ap[0][0], bfr[0], C[0], 0, 0, 0); \
        C[1] = __builtin_amdgcn_mfma_f32_16x16x32_f16(Ap[0][0], bfr[1], C[1], 0, 0, 0); \
        C[2] = __builtin_amdgcn_mfma_f32_16x16x32_f16(Ap[0][0], bfr[2], C[2], 0, 0, 0); \
        C[3] = __builtin_amdgcn_mfma_f32_16x16x32_f16(Ap[0][0], bfr[3], C[3], 0, 0, 0); \
        C[0] = __builtin_amdgcn_mfma_f32_16x16x32_f16(Ap[0][1], bfr[4], C[0], 0, 0, 0); \
        C[1] = __builtin_amdgcn_mfma_f32_16x16x32_f16(Ap[0][1], bfr[5], C[1], 0, 0, 0); \
        C[2] = __builtin_amdgcn_mfma_f32_16x16x32_f16(Ap[0][1], bfr[6], C[2], 0, 0, 0); \
        C[3] = __builtin_amdgcn_mfma_f32_16x16x32_f16(Ap[0][1], bfr[7], C[3], 0, 0, 0); \
    } while (0)

    // ---- prologue (step 0) ----
    half8_t Ap[2][2], Bp[2], Bq[2];
    f32x4 C[4] = {};
    Ap[0][0] = *(const half8_t*)&hbuf[0][((kt0 + 0) & 15) * 32 + aoff];
    Ap[0][1] = *(const half8_t*)&hbuf[0][((kt0 + 1) & 15) * 32 + aoff];
    CHUNK0_EXEC();
    Bp[0] = ldsB[(w * 16 + 0) * 64 + lane];   // chunk 1 odd pair
    Bp[1] = ldsB[(w * 16 + 1) * 64 + lane];
    Ap[1][0] = *(const half8_t*)&hbuf[0][((kt0 + 2) & 15) * 32 + aoff];
    Ap[1][1] = *(const half8_t*)&hbuf[0][((kt0 + 3) & 15) * 32 + aoff];
    Ap[0][0] = *(const half8_t*)&hbuf[0][((kt0 + 4) & 15) * 32 + aoff];
    Ap[0][1] = *(const half8_t*)&hbuf[0][((kt0 + 5) & 15) * 32 + aoff];
    float pvt = out[(size_t)b * DLAT + w * 64 + lane];    // P row t=0

    for (int t = 0; t < TSTEPS; ++t) {
        const int cur = t & 1, nxt = cur ^ 1;

        __builtin_amdgcn_s_setprio(1);
        #pragma unroll
        for (int c = 1; c < 8; ++c) {        // chunks 1..7 (chunk 0 pre-done)
            const int pb = c & 1;
            // even segment s = 2c
            if (c < 7) {
                #pragma unroll
                for (int nt = 0; nt < 4; ++nt)
                    C[nt] = __builtin_amdgcn_mfma_f32_16x16x32_f16(
                                Ap[pb][0], bfr[8 + (c - 1) * 6 + nt], C[nt], 0, 0, 0);
            } else {
                C[0] = __builtin_amdgcn_mfma_f32_16x16x32_f16(
                            Ap[pb][0], bfr[44], C[0], 0, 0, 0);
                C[1] = __builtin_amdgcn_mfma_f32_16x16x32_f16(
                            Ap[pb][0], bfr[45], C[1], 0, 0, 0);
                C[2] = __builtin_amdgcn_mfma_f32_16x16x32_f16(
                            Ap[pb][0], Bq[0], C[2], 0, 0, 0);
                C[3] = __builtin_amdgcn_mfma_f32_16x16x32_f16(
                            Ap[pb][0], Bq[1], C[3], 0, 0, 0);
            }
            // odd segment s = 2c+1: nt 0,1 reg; nt 2,3 prefetched LDS (Bp)
            {
                const int i0 = (c < 7) ? 8 + (c - 1) * 6 + 4 : 46;
                C[0] = __builtin_amdgcn_mfma_f32_16x16x32_f16(
                            Ap[pb][1], bfr[i0], C[0], 0, 0, 0);
                C[1] = __builtin_amdgcn_mfma_f32_16x16x32_f16(
                            Ap[pb][1], bfr[i0 + 1], C[1], 0, 0, 0);
                C[2] = __builtin_amdgcn_mfma_f32_16x16x32_f16(
                            Ap[pb][1], Bp[0], C[2], 0, 0, 0);
                C[3] = __builtin_amdgcn_mfma_f32_16x16x32_f16(
                            Ap[pb][1], Bp[1], C[3], 0, 0, 0);
            }
            if (c < 7) {                     // next chunk's odd pair
                Bp[0] = ldsB[(w * 16 + c * 2 + 0) * 64 + lane];
                Bp[1] = ldsB[(w * 16 + c * 2 + 1) * 64 + lane];
            }
            if (c == 4) {                    // chunk 7 even pair, 2 chunks early
                Bq[0] = ldsB[(w * 16 + 14) * 64 + lane];
                Bq[1] = ldsB[(w * 16 + 15) * 64 + lane];
            }
            if (c >= 1 && c < 6) {           // A-frags 2 chunks ahead (3..7)
                #pragma unroll
                for (int i = 0; i < 2; ++i) {
                    const int s = (c + 2) * 2 + i;
                    Ap[pb][i] =
                        *(const half8_t*)&hbuf[cur][((kt0 + s) & 15) * 32 + aoff];
                }
            }
        }
        __builtin_amdgcn_s_setprio(0);

        // epilogue: lane L owns n = 64w + L; all C rows equal (broadcast A)
        const int g4 = lane >> 4;
        float m = (g4 == 0) ? C[0][0]
                : (g4 == 1) ? C[1][0]
                : (g4 == 2) ? C[2][0]
                :             C[3][0];
        float v = fmaxf(m + pvt, 0.f);
        float* orow = out + ((size_t)t * BATCH + b) * DLAT;
        orow[w * 64 + lane] = v;             // HBM store: drains lazily
        hbuf[nxt][w * 64 + lane] = (_Float16)v;

        // ---- barrier-shadow tail: step t+1 chunk 0 (own slice, all-reg B) ----
        const int t2 = (t + 1 < TSTEPS) ? t + 1 : t;      // safe P prefetch
        pvt = out[((size_t)t2 * BATCH + b) * DLAT + w * 64 + lane];
        Ap[0][0] = *(const half8_t*)&hbuf[nxt][((kt0 + 0) & 15) * 32 + aoff];
        Ap[0][1] = *(const half8_t*)&hbuf[nxt][((kt0 + 1) & 15) * 32 + aoff];
        #pragma unroll
        for (int nt = 0; nt < 4; ++nt) C[nt] = (f32x4){0.f, 0.f, 0.f, 0.f};
        CHUNK0_EXEC();                       // no B LDS dependency in the shadow
        Bp[0] = ldsB[(w * 16 + 0) * 64 + lane];           // chunk 1 odd pair
        Bp[1] = ldsB[(w * 16 + 1) * 64 + lane];

        barrier_lds_only();                  // wait LDS only; not the HBM store

        // post-barrier: chunk 1 + 2 A-frags (other waves' h, now published)
        Ap[1][0] = *(const half8_t*)&hbuf[nxt][((kt0 + 2) & 15) * 32 + aoff];
        Ap[1][1] = *(const half8_t*)&hbuf[nxt][((kt0 + 3) & 15) * 32 + aoff];
        Ap[0][0] = *(const half8_t*)&hbuf[nxt][((kt0 + 4) & 15) * 32 + aoff];
        Ap[0][1] = *(const half8_t*)&hbuf[nxt][((kt0 + 5) & 15) * 32 + aoff];
    }
#undef CHUNK0_EXEC
}

// ---------------- Fallback (no workspace): row-major W_h, one row per thread ----
__global__ __launch_bounds__(512)
void rnn_scan_row(const float* __restrict__ Wh,
                  const float* __restrict__ h0,
                  float* __restrict__ out)
{
    __shared__ float h[DLAT];
    const int b = blockIdx.x;
    const int r = threadIdx.x;
    h[r] = h0[(size_t)b * DLAT + r];
    __syncthreads();
    const float* wrow = Wh + (size_t)r * DLAT;
    for (int t = 0; t < TSTEPS; ++t) {
        float* orow = out + ((size_t)t * BATCH + b) * DLAT;
        float acc = orow[r];
        #pragma unroll 8
        for (int k = 0; k < DLAT; k += 4) {
            float4 w  = *(const float4*)(wrow + k);
            float4 hv = *(const float4*)&h[k];
            acc += w.x*hv.x + w.y*hv.y + w.z*hv.z + w.w*hv.w;
        }
        float v = fmaxf(acc, 0.f);
        __syncthreads();
        h[r] = v;
        orow[r] = v;
        __syncthreads();
    }
}

extern "C" void kernel_launch(void* const* d_in, const int* in_sizes, int n_in,
                              void* d_out, int out_size, void* d_ws, size_t ws_size,
                              hipStream_t stream)
{
    const float* x    = (const float*)d_in[0];
    const float* h0   = (const float*)d_in[1];
    const float* Win  = (const float*)d_in[2];
    const float* Wh   = (const float*)d_in[3];
    const float* bh   = (const float*)d_in[4];
    float* out = (float*)d_out;

    if (ws_size >= WS_TIER1) {
        _Float16* Wm = (_Float16*)d_ws;
        _Float16* Wf = (_Float16*)((char*)d_ws + WS_WF_OFF);
        pack_both<<<192, 256, 0, stream>>>(Wh, Wm, Win, Wf);
        precompute_mfma<<<1024, 256, 0, stream>>>(x, (const half8_t*)Wf, bh, out);
        rnn_scan_c0<<<BATCH, 512, 0, stream>>>((const half8_t*)Wm, h0, out);
    } else if (ws_size >= WS_TIER2) {
        _Float16* Wm = (_Float16*)d_ws;
        dim3 gA(DLAT / BN, (TSTEPS * BATCH) / BM);   // (8, 512)
        pack_both<<<128, 256, 0, stream>>>(Wh, Wm, Win, (_Float16*)nullptr);
        precompute_gemm<<<gA, 256, 0, stream>>>(x, Win, bh, out);
        rnn_scan_c0<<<BATCH, 512, 0, stream>>>((const half8_t*)Wm, h0, out);
    } else {
        dim3 gA(DLAT / BN, (TSTEPS * BATCH) / BM);
        precompute_gemm<<<gA, 256, 0, stream>>>(x, Win, bh, out);
        rnn_scan_row<<<BATCH, 512, 0, stream>>>(Wh, h0, out);
    }
}